// Round 1
// baseline (831.774 us; speedup 1.0000x reference)
//
#include <hip/hip_runtime.h>

#define FCOUNT 786432  // 12 * 256 * 256

// ---------------------------------------------------------------------------
// pos init: pos[:] = -1 (vectorized int4 stores, grid-stride)
__global__ void init_pos_kernel(int* __restrict__ pos, long long n4) {
    long long t = (long long)blockIdx.x * blockDim.x + threadIdx.x;
    long long stride = (long long)gridDim.x * blockDim.x;
    int4 v = make_int4(-1, -1, -1, -1);
    for (long long i = t; i < n4; i += stride)
        reinterpret_cast<int4*>(pos)[i] = v;
}

// out row 1 (gt_matches1) init to -1.0f for all b
__global__ void init_out1_kernel(float* __restrict__ out, int N) {
    int b = blockIdx.y;
    int j = blockIdx.x * blockDim.x + threadIdx.x;
    if (j < N) out[(size_t)b * 3 * N + N + j] = -1.0f;
}

// pos[b][idx1[b][j]] = max j  (last-write-wins == max since values are arange)
__global__ void scatter_pos_kernel(const int* __restrict__ idx1,
                                   int* __restrict__ pos, int N, int b0) {
    int b = blockIdx.y;          // chunk-local b
    int j = blockIdx.x * blockDim.x + threadIdx.x;
    if (j < N) {
        int f = idx1[(size_t)(b0 + b) * N + j];
        atomicMax(&pos[(size_t)b * FCOUNT + f], j);
    }
}

// main: gm0 = corr>=0 ? pos[corr[idx0]] : -1 ; rows 0,2 direct; row1 scatter
__global__ void main_kernel(const int* __restrict__ corr,
                            const int* __restrict__ idx0,
                            const float* __restrict__ scores,
                            const int* __restrict__ pos,
                            float* __restrict__ out, int N, int b0) {
    int b = blockIdx.y;          // chunk-local b
    int gb = b0 + b;             // global b
    int j = blockIdx.x * blockDim.x + threadIdx.x;
    if (j >= N) return;
    int f0 = idx0[(size_t)gb * N + j];
    int c = corr[(size_t)gb * FCOUNT + f0];
    int gm0 = -1;
    if (c >= 0) gm0 = pos[(size_t)b * FCOUNT + c];
    size_t obase = (size_t)gb * 3 * N;
    out[obase + j] = (float)gm0;
    out[obase + 2 * N + j] = (gm0 >= 0) ? scores[(size_t)gb * N + j] : 0.0f;
    if (gm0 >= 0) {
        // float atomicMax via signed-int bits: all stored values are floats of
        // non-negative ints (bit-monotone); init -1.0f has negative int bits.
        atomicMax(reinterpret_cast<int*>(&out[obase + N + gm0]),
                  __float_as_int((float)j));
    }
}

extern "C" void kernel_launch(void* const* d_in, const int* in_sizes, int n_in,
                              void* d_out, int out_size, void* d_ws, size_t ws_size,
                              hipStream_t stream) {
    const int*   corr   = (const int*)d_in[0];
    const int*   idx0   = (const int*)d_in[1];
    const int*   idx1   = (const int*)d_in[2];
    const float* scores = (const float*)d_in[3];
    float* out = (float*)d_out;

    const int BF = in_sizes[0];
    const int BN = in_sizes[1];
    const int B  = BF / FCOUNT;
    const int N  = BN / B;

    int* pos = (int*)d_ws;
    // How many pairs' pos arrays fit in the workspace at once
    size_t per_b_bytes = (size_t)FCOUNT * sizeof(int);
    int chunkB = (int)(ws_size / per_b_bytes);
    if (chunkB < 1) chunkB = 1;          // hope ws >= 3 MB
    if (chunkB > B) chunkB = B;

    dim3 blk(256);
    int nblk = (N + 255) / 256;

    init_out1_kernel<<<dim3(nblk, B), blk, 0, stream>>>(out, N);

    for (int b0 = 0; b0 < B; b0 += chunkB) {
        int nb = (b0 + chunkB <= B) ? chunkB : (B - b0);
        long long n4 = (long long)nb * FCOUNT / 4;
        init_pos_kernel<<<dim3(2048), blk, 0, stream>>>(pos, n4);
        scatter_pos_kernel<<<dim3(nblk, nb), blk, 0, stream>>>(idx1, pos, N, b0);
        main_kernel<<<dim3(nblk, nb), blk, 0, stream>>>(corr, idx0, scores, pos,
                                                        out, N, b0);
    }
}

// Round 2
// 590.754 us; speedup vs baseline: 1.4080x; 1.4080x over previous
//
#include <hip/hip_runtime.h>

#define FCOUNT 786432   // 12 * 256 * 256
#define SEGBITS 13
#define SEG 8192        // facets per segment
#define NSEG 96         // FCOUNT / SEG
#define JBITS 18
#define JMASK ((1 << JBITS) - 1)
#define ITEMS 16        // items per thread in binning kernels

// ---------------------------------------------------------------------------
// binA: bin idx1 entries (facet f1, position g) into per-(pair,segment)
// buckets. Packed entry: (f1 & 8191) << 18 | g.  (N < 2^18, SEG = 2^13.)
__global__ __launch_bounds__(256) void binA_kernel(
        const int* __restrict__ idx1, int* __restrict__ cnt,
        int* __restrict__ bucket, int N, int nchunk, int cap) {
    __shared__ int hist[NSEG];
    __shared__ int base[NSEG];
    __shared__ int cur[NSEG];
    int id = blockIdx.x;
    int xcd = id & 7, k = id >> 3;          // pin pair b (b%8==xcd) to one XCD
    int b = xcd + 8 * (k / nchunk);
    int chunk = k % nchunk;
    int tid = threadIdx.x;
    for (int t = tid; t < NSEG; t += 256) { hist[t] = 0; cur[t] = 0; }
    __syncthreads();
    int f[ITEMS];
    #pragma unroll
    for (int i = 0; i < ITEMS; i++) {
        int j = chunk * (256 * ITEMS) + i * 256 + tid;
        f[i] = -1;
        if (j < N) {
            int fv = idx1[(size_t)b * N + j];
            f[i] = fv;
            atomicAdd(&hist[fv >> SEGBITS], 1);
        }
    }
    __syncthreads();
    for (int t = tid; t < NSEG; t += 256)
        base[t] = hist[t] ? atomicAdd(&cnt[b * NSEG + t], hist[t]) : 0;
    __syncthreads();
    #pragma unroll
    for (int i = 0; i < ITEMS; i++) {
        if (f[i] >= 0) {
            int j = chunk * (256 * ITEMS) + i * 256 + tid;
            int s = f[i] >> SEGBITS;
            int slot = base[s] + atomicAdd(&cur[s], 1);
            if (slot < cap)
                bucket[((size_t)b * NSEG + s) * cap + slot] =
                    ((f[i] & (SEG - 1)) << JBITS) | j;
        }
    }
}

// ---------------------------------------------------------------------------
// binB: c = corr[idx0[j]]; invalid c -> write out rows 0/2 directly;
// valid c -> bin (c, j).  XCD-pinned so each pair's 3 MB corr row has L2 reuse.
__global__ __launch_bounds__(256) void binB_kernel(
        const int* __restrict__ corr, const int* __restrict__ idx0,
        int* __restrict__ cnt, int* __restrict__ bucket,
        float* __restrict__ out, int N, int nchunk, int cap) {
    __shared__ int hist[NSEG];
    __shared__ int base[NSEG];
    __shared__ int cur[NSEG];
    int id = blockIdx.x;
    int xcd = id & 7, k = id >> 3;
    int b = xcd + 8 * (k / nchunk);
    int chunk = k % nchunk;
    int tid = threadIdx.x;
    for (int t = tid; t < NSEG; t += 256) { hist[t] = 0; cur[t] = 0; }
    __syncthreads();
    size_t obase = (size_t)b * 3 * N;
    int c[ITEMS];
    #pragma unroll
    for (int i = 0; i < ITEMS; i++) {
        int j = chunk * (256 * ITEMS) + i * 256 + tid;
        c[i] = -1;
        if (j < N) {
            int f0 = idx0[(size_t)b * N + j];
            int cv = corr[(size_t)b * FCOUNT + f0];
            if (cv >= 0) {
                c[i] = cv;
                atomicAdd(&hist[cv >> SEGBITS], 1);
            } else {
                out[obase + j] = -1.0f;          // gt_matches0
                out[obase + 2 * N + j] = 0.0f;   // masked score
            }
        }
    }
    __syncthreads();
    for (int t = tid; t < NSEG; t += 256)
        base[t] = hist[t] ? atomicAdd(&cnt[b * NSEG + t], hist[t]) : 0;
    __syncthreads();
    #pragma unroll
    for (int i = 0; i < ITEMS; i++) {
        if (c[i] >= 0) {
            int j = chunk * (256 * ITEMS) + i * 256 + tid;
            int s = c[i] >> SEGBITS;
            int slot = base[s] + atomicAdd(&cur[s], 1);
            if (slot < cap)
                bucket[((size_t)b * NSEG + s) * cap + slot] =
                    ((c[i] & (SEG - 1)) << JBITS) | j;
        }
    }
}

// ---------------------------------------------------------------------------
// passC: per (pair, segment): build pos (inverse of idx1) and maxq
// (max j with c(j)=f) in LDS, then write all three output rows with plain
// stores.  gt_matches1[g] = (pos[idx1[g]]==g) ? maxq[idx1[g]] : -1.
__global__ __launch_bounds__(256) void passC_kernel(
        const int* __restrict__ cntA, const int* __restrict__ bucketA,
        const int* __restrict__ cntB, const int* __restrict__ bucketB,
        const float* __restrict__ scores, float* __restrict__ out,
        int N, int cap) {
    __shared__ int posv[SEG];   // 32 KB
    __shared__ int maxq[SEG];   // 32 KB
    int id = blockIdx.x;
    int xcd = id & 7, k = id >> 3;
    int b = xcd + 8 * (k / NSEG);
    int s = k % NSEG;
    int tid = threadIdx.x;
    for (int t = tid; t < SEG; t += 256) { posv[t] = -1; maxq[t] = -1; }
    __syncthreads();
    int nA = cntA[b * NSEG + s]; if (nA > cap) nA = cap;
    int nB = cntB[b * NSEG + s]; if (nB > cap) nB = cap;
    const int* bA = &bucketA[((size_t)b * NSEG + s) * cap];
    const int* bB = &bucketB[((size_t)b * NSEG + s) * cap];
    for (int i = tid; i < nA; i += 256) {
        int e = bA[i];
        atomicMax(&posv[e >> JBITS], e & JMASK);
    }
    for (int i = tid; i < nB; i += 256) {
        int e = bB[i];
        atomicMax(&maxq[e >> JBITS], e & JMASK);
    }
    __syncthreads();
    size_t obase = (size_t)b * 3 * N;
    for (int i = tid; i < nB; i += 256) {
        int e = bB[i];
        int f = e >> JBITS, j = e & JMASK;
        int g = posv[f];
        out[obase + j] = (float)g;
        out[obase + 2 * N + j] = (g >= 0) ? scores[(size_t)b * N + j] : 0.0f;
    }
    for (int i = tid; i < nA; i += 256) {
        int e = bA[i];
        int f = e >> JBITS, g = e & JMASK;
        out[obase + N + g] = (posv[f] == g) ? (float)maxq[f] : -1.0f;
    }
}

// ---------------------------------------------------------------------------
extern "C" void kernel_launch(void* const* d_in, const int* in_sizes, int n_in,
                              void* d_out, int out_size, void* d_ws, size_t ws_size,
                              hipStream_t stream) {
    const int*   corr   = (const int*)d_in[0];
    const int*   idx0   = (const int*)d_in[1];
    const int*   idx1   = (const int*)d_in[2];
    const float* scores = (const float*)d_in[3];
    float* out = (float*)d_out;

    const int B = in_sizes[0] / FCOUNT;   // 64 (must be multiple of 8)
    const int N = in_sizes[1] / B;        // 200000 (< 2^18)

    const int nbkt = B * NSEG;
    int* cntA = (int*)d_ws;
    int* cntB = cntA + nbkt;
    size_t head = (size_t)2 * nbkt * sizeof(int);
    // bucket capacity from remaining ws; expected load ~N/NSEG = 2083/bucket
    long long cap_ll = (long long)((ws_size - head) / ((size_t)2 * nbkt * sizeof(int)));
    int cap = (cap_ll > 8192) ? 8192 : (int)cap_ll;
    int* bucketA = cntB + nbkt;
    int* bucketB = bucketA + (size_t)nbkt * cap;

    hipMemsetAsync(cntA, 0, head, stream);

    int nchunk = (N + 256 * ITEMS - 1) / (256 * ITEMS);
    int nblk = B * nchunk;
    binA_kernel<<<nblk, 256, 0, stream>>>(idx1, cntA, bucketA, N, nchunk, cap);
    binB_kernel<<<nblk, 256, 0, stream>>>(corr, idx0, cntB, bucketB, out, N, nchunk, cap);
    passC_kernel<<<B * NSEG, 256, 0, stream>>>(cntA, bucketA, cntB, bucketB,
                                               scores, out, N, cap);
}